// Round 1
// 426.909 us; speedup vs baseline: 1.0006x; 1.0006x over previous
//
#include <hip/hip_runtime.h>
#include <cstdint>
#include <cstddef>

#define BB 128
#define TT 512
#define DD 100
#define HH 100
#define NG 400   // 4*H
#define LL 25
#define TS 32    // scan tile (steps per burst)
#define NTILE 16
#define F_LOG2E 1.44269504088896340736f
#define F_LN2   0.69314718055994530942f

typedef __decltype(__builtin_amdgcn_cvt_pkrtz(0.f, 0.f)) h2_t;
typedef _Float16 v8h __attribute__((ext_vector_type(8)));
typedef float v4f __attribute__((ext_vector_type(4)));

__device__ __forceinline__ h2_t bc_h2(unsigned int u) {
  return __builtin_bit_cast(h2_t, u);
}
__device__ __forceinline__ unsigned int pk(float x, float y) {
  return __builtin_bit_cast(unsigned int, __builtin_amdgcn_cvt_pkrtz(x, y));
}

__device__ __forceinline__ float fdot2(h2_t a, h2_t b, float c) {
#if __has_builtin(__builtin_amdgcn_fdot2)
  return __builtin_amdgcn_fdot2(a, b, c, false);
#else
  return c + (float)a[0] * (float)b[0] + (float)a[1] * (float)b[1];
#endif
}

__device__ __forceinline__ float fexp2(float x) { return __builtin_amdgcn_exp2f(x); }
__device__ __forceinline__ float flog2(float x) { return __builtin_amdgcn_logf(x); }
__device__ __forceinline__ float frcp(float x)  { return __builtin_amdgcn_rcpf(x); }

__device__ __forceinline__ float sigmoid_f(float x) {
  return frcp(1.f + fexp2(-F_LOG2E * x));
}
__device__ __forceinline__ float tanh_f(float x) {
  float e = fexp2(2.f * F_LOG2E * x);
  return 1.f - 2.f * frcp(e + 1.f);
}

template <int CTRL>
__device__ __forceinline__ float qadd(float v) {
#if __has_builtin(__builtin_amdgcn_mov_dpp)
  int m = __builtin_amdgcn_mov_dpp(__builtin_bit_cast(int, v), CTRL, 0xF, 0xF, true);
  return v + __builtin_bit_cast(float, m);
#else
  int x = (CTRL == 177) ? 1 : 2;
  return v + __shfl_xor(v, x);
#endif
}

template <int LANE>
__device__ __forceinline__ float qbcast(float v) {
#if __has_builtin(__builtin_amdgcn_mov_dpp)
  int m = __builtin_amdgcn_mov_dpp(__builtin_bit_cast(int, v), LANE * 0x55, 0xF, 0xF, true);
  return __builtin_bit_cast(float, m);
#else
  return __shfl(v, (threadIdx.x & 63 & ~3) + LANE);
#endif
}

__device__ __forceinline__ float rfl(float v) {
  return __builtin_bit_cast(float,
      __builtin_amdgcn_readfirstlane(__builtin_bit_cast(int, v)));
}

__device__ __forceinline__ void wave_fence() {
#if __has_builtin(__builtin_amdgcn_wave_barrier)
  __builtin_amdgcn_wave_barrier();
#endif
}

// LDS-visibility-only barrier (vmcnt left free): imm 0xC07F.
__device__ __forceinline__ void lds_barrier() {
  __builtin_amdgcn_s_waitcnt(0xC07F);
  __builtin_amdgcn_s_barrier();
}

// ---------------------------------------------------------------------------
// FUSED BiLSTM + x-GEMM + emissions (v3 — best measured: 300 us). UNCHANGED.
// ---------------------------------------------------------------------------
__global__ __launch_bounds__(512, 2) void lstm_fused3(
    const int* __restrict__ tok, const float* __restrict__ emb,
    const float* __restrict__ w_ih_f, const float* __restrict__ w_ih_b,
    const float* __restrict__ b_ih_f, const float* __restrict__ b_hh_f,
    const float* __restrict__ b_ih_b, const float* __restrict__ b_hh_b,
    const float* __restrict__ w_hh_f, const float* __restrict__ w_hh_b,
    const float* __restrict__ w_tag, const float* __restrict__ b_tag,
    float* __restrict__ em_f, float* __restrict__ em_b)
{
  const int tid = threadIdx.x;
  const int b   = blockIdx.x & 127;
  const int dir = blockIdx.x >> 7;
  const float* w_hh = dir ? w_hh_b : w_hh_f;
  const float* w_ih = dir ? w_ih_b : w_ih_f;
  const float* b_ih = dir ? b_ih_b : b_ih_f;
  const float* b_hh = dir ? b_hh_b : b_hh_f;

  __shared__ __align__(16) unsigned short gin_lds[TS * 400];   // 25.6 KB
  __shared__ __align__(16) unsigned int xlds[TS * 68];         // 8.7 KB
  __shared__ __align__(16) unsigned int hls0[52];
  __shared__ __align__(16) unsigned int hls1[52];

  // burst lane mapping
  const int wv   = tid >> 6;
  const int lane = tid & 63;
  const int l16  = lane & 15;
  const int quad = lane >> 4;
  const int c0b  = (25 * wv) >> 3;
  const int c1b  = (25 * (wv + 1)) >> 3;
  const int ncol = c1b - c0b;   // 3 or 4

  // ---- one-time: B fragments from global w_ih into registers ----
  v8h bfr[4][4];
  int pcol[4];
#pragma unroll
  for (int ci = 0; ci < 4; ++ci) {
    const int cc = (ci < ncol) ? (c0b + ci) : c0b;
    const int n  = 16 * cc + l16;
    const float* wr = w_ih + (size_t)n * DD;
#pragma unroll
    for (int f = 0; f < 3; ++f) {
      const float* wp = wr + f * 32 + quad * 8;
      float4 va = *(const float4*)(wp);
      float4 vb = *(const float4*)(wp + 4);
      uint4 u;
      u.x = pk(va.x, va.y); u.y = pk(va.z, va.w);
      u.z = pk(vb.x, vb.y); u.w = pk(vb.z, vb.w);
      bfr[ci][f] = __builtin_bit_cast(v8h, u);
    }
    {
      uint4 u = {0u, 0u, 0u, 0u};
      if (quad == 0) {
        float4 va = *(const float4*)(wr + 96);
        u.x = pk(va.x, va.y); u.y = pk(va.z, va.w);
      }
      bfr[ci][3] = __builtin_bit_cast(v8h, u);
    }
    const int qn = (n * 41) >> 12;            // n/100 for n<400
    pcol[ci] = ((n - 100 * qn) << 2) + qn;    // store permutation
  }

  // ---- xlds K-pad zero ----
  for (int i = tid; i < TS * 18; i += 512) {
    int row = i / 18;
    int d = i - row * 18;
    xlds[row * 68 + 50 + d] = 0u;
  }

  // ---- scan state (v6) ----
  const bool uact = tid < NG;
  const int j = tid >> 2;
  const int s = tid & 3;
  const int od = 12 * s;
  const int nnv = (s == 3) ? 14 : 12;

  h2_t wA[14], wB[14], wC[14], wD[14];
  float bias = 0.f;
  if (uact) {
#pragma unroll
    for (int d = 0; d < 14; ++d) {
      int dd = (d < nnv) ? (od + d) : 0;
      const float* r0 = w_hh + (size_t)(0 * 100 + j) * HH + 2 * dd;
      const float* r1 = w_hh + (size_t)(1 * 100 + j) * HH + 2 * dd;
      const float* r2 = w_hh + (size_t)(2 * 100 + j) * HH + 2 * dd;
      const float* r3 = w_hh + (size_t)(3 * 100 + j) * HH + 2 * dd;
      h2_t z = __builtin_amdgcn_cvt_pkrtz(0.f, 0.f);
      wA[d] = (d < nnv) ? __builtin_amdgcn_cvt_pkrtz(r0[0], r0[1]) : z;
      wB[d] = (d < nnv) ? __builtin_amdgcn_cvt_pkrtz(r1[0], r1[1]) : z;
      wC[d] = (d < nnv) ? __builtin_amdgcn_cvt_pkrtz(r2[0], r2[1]) : z;
      wD[d] = (d < nnv) ? __builtin_amdgcn_cvt_pkrtz(r3[0], r3[1]) : z;
    }
    bias = b_ih[s * 100 + j] + b_hh[s * 100 + j];
  }
  const float kk2 = (s == 2) ? (2.f * F_LOG2E) : (-F_LOG2E);
  const float cA  = (s == 2) ? -2.f : 1.f;
  const float cB  = (s == 2) ? 1.f : 0.f;

  // emission lanes: wave 7
  const int el = tid - 448;
  const bool eact = (el >= 0) && (el < 50);
  const int l  = (el >= 0) ? (el >> 1) : 0;
  const int hf = (el >= 0) ? (el & 1) : 0;
  const int eo = hf ? 24 : 0;
  const int en = hf ? 26 : 24;
  h2_t wt[26];
  float bt = 0.f;
  if (eact) {
    const float* wr = w_tag + (size_t)l * 200 + dir * 100;
#pragma unroll
    for (int d = 0; d < 26; ++d) {
      int dd = (d < en) ? (eo + d) : 0;
      h2_t z = __builtin_amdgcn_cvt_pkrtz(0.f, 0.f);
      wt[d] = (d < en) ? __builtin_amdgcn_cvt_pkrtz(wr[2 * dd], wr[2 * dd + 1]) : z;
    }
    if (dir == 0 && hf == 0) bt = b_tag[l];
  }
  float* emo = dir ? em_b : em_f;
  float* emp = emo + ((size_t)b * TT + (dir ? (TT - 1) : 0)) * LL + l;
  const ptrdiff_t estep = dir ? -(ptrdiff_t)LL : (ptrdiff_t)LL;

  if (tid < 52) { hls0[tid] = 0u; hls1[tid] = 0u; }

  // x staging mapping: thread t<416 covers (row = t/13, seg = t%13)
  const int tprow = tid / 13;
  const int tps   = tid - 13 * tprow;
  const bool tp_act = tid < 416;

  // initial x prefetch (tile 0)
  float4 xa = {0, 0, 0, 0}, xb = {0, 0, 0, 0};
  if (tp_act) {
    int ii = tprow;
    int tt = dir ? (TT - 1 - ii) : ii;
    int tk = tok[b * TT + tt];
    const float* xp = emb + (size_t)tk * DD + 8 * tps;
    xa = *(const float4*)xp;
    if (tps < 12) xb = *(const float4*)(xp + 4);
  }

  float c = 0.f;
  unsigned short gnext = 0;
  int grow = 0;

#define SDOT(d, hh) \
  p0 = fdot2(wA[d], bc_h2(hh), p0); p1 = fdot2(wB[d], bc_h2(hh), p1); \
  p2 = fdot2(wC[d], bc_h2(hh), p2); p3 = fdot2(wD[d], bc_h2(hh), p3);
#define EDOT(d, hh) { h2_t h = bc_h2(hh); \
  if ((d & 3) == 0) a0 = fdot2(wt[d], h, a0); \
  else if ((d & 3) == 1) a1 = fdot2(wt[d], h, a1); \
  else if ((d & 3) == 2) a2 = fdot2(wt[d], h, a2); \
  else a3 = fdot2(wt[d], h, a3); }

#define SCAN_STEP(HRD, HWR, TVNZ)                                          \
  {                                                                        \
    if (uact) {                                                            \
      unsigned short gcurr = gnext;                                        \
      int nr = (grow < TS - 1) ? grow + 1 : TS - 1;                        \
      gnext = gin_lds[nr * 400 + tid];                                     \
      grow = nr;                                                           \
      const unsigned int* hp = (HRD) + od;                                 \
      uint4 u0 = *((const uint4*)hp);                                      \
      uint4 u1 = *((const uint4*)(hp + 4));                                \
      uint4 u2 = *((const uint4*)(hp + 8));                                \
      uint2 u3 = *((const uint2*)(hp + 12));                               \
      float p0, p1, p2, p3;                                                \
      p0 = fdot2(wA[0], bc_h2(u0.x), 0.f);                                 \
      p1 = fdot2(wB[0], bc_h2(u0.x), 0.f);                                 \
      p2 = fdot2(wC[0], bc_h2(u0.x), 0.f);                                 \
      p3 = fdot2(wD[0], bc_h2(u0.x), 0.f);                                 \
      SDOT(1, u0.y)  SDOT(2, u0.z)  SDOT(3, u0.w)                          \
      SDOT(4, u1.x)  SDOT(5, u1.y)  SDOT(6, u1.z)  SDOT(7, u1.w)           \
      SDOT(8, u2.x)  SDOT(9, u2.y)  SDOT(10, u2.z) SDOT(11, u2.w)          \
      SDOT(12, u3.x) SDOT(13, u3.y)                                        \
      p0 = qadd<78>(qadd<177>(p0));                                        \
      p1 = qadd<78>(qadd<177>(p1));                                        \
      p2 = qadd<78>(qadd<177>(p2));                                        \
      p3 = qadd<78>(qadd<177>(p3));                                        \
      float psel = (s == 0) ? p0 : (s == 1) ? p1 : (s == 2) ? p2 : p3;     \
      float gate = psel + bias + (float)__builtin_bit_cast(__fp16, gcurr); \
      float y  = fexp2(kk2 * gate);                                        \
      float rr = frcp(1.f + y);                                            \
      float actv = fmaf(cA, rr, cB);                                       \
      float iv = qbcast<0>(actv);                                          \
      float fv = qbcast<1>(actv);                                          \
      float gv = qbcast<2>(actv);                                          \
      float ov = qbcast<3>(actv);                                          \
      c = fmaf(fv, c, iv * gv);                                            \
      float hvv = ov * tanh_f(c);                                          \
      if (s == 0) ((__fp16*)(HWR))[j] = (__fp16)hvv;                       \
    } else if (eact && (TVNZ)) {                                           \
      const unsigned int* hp = (HRD) + eo;                                 \
      uint4 e0 = *((const uint4*)hp);                                      \
      uint4 e1 = *((const uint4*)(hp + 4));                                \
      uint4 e2 = *((const uint4*)(hp + 8));                                \
      uint4 e3 = *((const uint4*)(hp + 12));                               \
      uint4 e4 = *((const uint4*)(hp + 16));                               \
      uint4 e5 = *((const uint4*)(hp + 20));                               \
      uint2 e6 = *((const uint2*)(hp + 24));                               \
      float a0, a1, a2, a3;                                                \
      a0 = fdot2(wt[0], bc_h2(e0.x), 0.f);                                 \
      a1 = fdot2(wt[1], bc_h2(e0.y), 0.f);                                 \
      a2 = fdot2(wt[2], bc_h2(e0.z), 0.f);                                 \
      a3 = fdot2(wt[3], bc_h2(e0.w), 0.f);                                 \
      EDOT(4, e1.x)  EDOT(5, e1.y)  EDOT(6, e1.z)  EDOT(7, e1.w)           \
      EDOT(8, e2.x)  EDOT(9, e2.y)  EDOT(10, e2.z) EDOT(11, e2.w)          \
      EDOT(12, e3.x) EDOT(13, e3.y) EDOT(14, e3.z) EDOT(15, e3.w)          \
      EDOT(16, e4.x) EDOT(17, e4.y) EDOT(18, e4.z) EDOT(19, e4.w)          \
      EDOT(20, e5.x) EDOT(21, e5.y) EDOT(22, e5.z) EDOT(23, e5.w)          \
      EDOT(24, e6.x) EDOT(25, e6.y)                                        \
      float ss = (a0 + a1) + (a2 + a3);                                    \
      float tot = qadd<177>(ss);                                           \
      if (hf == 0) *emp = tot + bt;                                        \
      emp += estep;                                                        \
    }                                                                      \
    lds_barrier();                                                         \
  }

  __syncthreads();  // xlds-pad / hls init complete

  for (int T = 0; T < NTILE; ++T) {
    // ---- write prefetched x regs to xlds ----
    if (tp_act) {
      unsigned int* xr = xlds + tprow * 68 + 4 * tps;
      if (tps < 12) {
        uint4 u;
        u.x = pk(xa.x, xa.y); u.y = pk(xa.z, xa.w);
        u.z = pk(xb.x, xb.y); u.w = pk(xb.z, xb.w);
        *(uint4*)xr = u;
      } else {
        xr[0] = pk(xa.x, xa.y);
        xr[1] = pk(xa.z, xa.w);
      }
    }
    __syncthreads();

    // ---- BURST ----
    {
      v8h af[2][4];
#pragma unroll
      for (int rg = 0; rg < 2; ++rg)
#pragma unroll
        for (int f = 0; f < 4; ++f)
          af[rg][f] = __builtin_bit_cast(v8h,
              *(const uint4*)(xlds + (rg * 16 + l16) * 68 + f * 16 + quad * 4));

      // kick off next tile's x prefetch (stays in flight through the scan)
      if (tp_act && T + 1 < NTILE) {
        int ii = (T + 1) * TS + tprow;
        int tt = dir ? (TT - 1 - ii) : ii;
        int tk = tok[b * TT + tt];
        const float* xp = emb + (size_t)tk * DD + 8 * tps;
        xa = *(const float4*)xp;
        if (tps < 12) xb = *(const float4*)(xp + 4);
      }

      __fp16* gout = (__fp16*)gin_lds;
#pragma unroll
      for (int ci = 0; ci < 4; ++ci) {
        if (ci >= ncol) break;
        const int p = pcol[ci];
#pragma unroll
        for (int rg = 0; rg < 2; ++rg) {
          v4f acc = {0.f, 0.f, 0.f, 0.f};
          acc = __builtin_amdgcn_mfma_f32_16x16x32_f16(af[rg][0], bfr[ci][0], acc, 0, 0, 0);
          acc = __builtin_amdgcn_mfma_f32_16x16x32_f16(af[rg][1], bfr[ci][1], acc, 0, 0, 0);
          acc = __builtin_amdgcn_mfma_f32_16x16x32_f16(af[rg][2], bfr[ci][2], acc, 0, 0, 0);
          acc = __builtin_amdgcn_mfma_f32_16x16x32_f16(af[rg][3], bfr[ci][3], acc, 0, 0, 0);
          const int rowb = rg * 16 + quad * 4;
#pragma unroll
          for (int r = 0; r < 4; ++r)
            gout[(rowb + r) * 400 + p] = (__fp16)acc[r];
        }
      }
    }
    __syncthreads();
    if (uact) { grow = 0; gnext = gin_lds[tid]; }

    // ---- TS scan steps ----
    SCAN_STEP(hls0, hls1, (T > 0))
    SCAN_STEP(hls1, hls0, true)
    for (int it = 1; it < TS / 2; ++it) {
      SCAN_STEP(hls0, hls1, true)
      SCAN_STEP(hls1, hls0, true)
    }
  }
#undef SCAN_STEP
#undef SDOT

  // epilogue: emission for the last h (in hls0)
  if (eact) {
    const unsigned int* hp = hls0 + eo;
    uint4 e0 = *((const uint4*)hp);
    uint4 e1 = *((const uint4*)(hp + 4));
    uint4 e2 = *((const uint4*)(hp + 8));
    uint4 e3 = *((const uint4*)(hp + 12));
    uint4 e4 = *((const uint4*)(hp + 16));
    uint4 e5 = *((const uint4*)(hp + 20));
    uint2 e6 = *((const uint2*)(hp + 24));
    float a0, a1, a2, a3;
    a0 = fdot2(wt[0], bc_h2(e0.x), 0.f);
    a1 = fdot2(wt[1], bc_h2(e0.y), 0.f);
    a2 = fdot2(wt[2], bc_h2(e0.z), 0.f);
    a3 = fdot2(wt[3], bc_h2(e0.w), 0.f);
    EDOT(4, e1.x)  EDOT(5, e1.y)  EDOT(6, e1.z)  EDOT(7, e1.w)
    EDOT(8, e2.x)  EDOT(9, e2.y)  EDOT(10, e2.z) EDOT(11, e2.w)
    EDOT(12, e3.x) EDOT(13, e3.y) EDOT(14, e3.z) EDOT(15, e3.w)
    EDOT(16, e4.x) EDOT(17, e4.y) EDOT(18, e4.z) EDOT(19, e4.w)
    EDOT(20, e5.x) EDOT(21, e5.y) EDOT(22, e5.z) EDOT(23, e5.w)
    EDOT(24, e6.x) EDOT(25, e6.y)
    float ss = (a0 + a1) + (a2 + a3);
    float tot = qadd<177>(ss);
    if (hf == 0) {
      int ttp = dir ? 0 : (TT - 1);
      emo[((size_t)b * TT + ttp) * LL + l] = tot + bt;
    }
  }
#undef EDOT
}

// ===========================================================================
// CRF v3 — parallel chunked scan.
// The forward algorithm is a chain of 25x25 positive matrix products in the
// exp domain: logZ = log( alpha0 . M_1 . M_2 ... M_511 . exp(end) ), with
// M_t[i][j] = exp(T[i][j]) * exp(em_t[j]).  Matrix product is associative:
//  - crf_chunks: 128 b x 8 chunks = 1024 blocks. Each block sequentially
//    multiplies its 64 (chunk 0: 63) step matrices into P_c (f32, with a
//    fixed 2^-5 per-step scale folded into E' = exp(T)*2^-5 to stay in f32
//    range). Stored transposed, rows padded to 28, in a static device buffer.
//  - crf_combine: per batch, alpha0 through the 8 chunk matrices with
//    per-chunk exponent renormalization + end; wave 1 computes the gold
//    score in parallel. atomicAdd both into d_out (pre-zeroed).
// ===========================================================================
#define CHN  8
#define CLEN 64
__device__ __align__(16) float g_PT[(size_t)BB * CHN * LL * 28];  // 2.87 MB

__global__ __launch_bounds__(128, 2) void crf_chunks(
    const float* __restrict__ em_f, const float* __restrict__ em_b,
    const float* __restrict__ trans)
{
  const int tid = threadIdx.x;
  const int b   = blockIdx.x >> 3;
  const int c   = blockIdx.x & 7;
  const int ts  = c * CLEN;

  __shared__ __align__(16) float Al[2][LL][28];   // double-buffered A
  __shared__ __align__(16) float el[CLEN][32];    // e_t[j] = exp(em_t[j])

  // ---- stage e rows (2 threads per time step) ----
  {
    const int row  = tid >> 1;        // 0..63
    const int half = tid & 1;
    const int jb   = half ? 13 : 0;
    const int nj   = half ? 12 : 13;
    const float* pf = em_f + ((size_t)b * TT + ts + row) * LL;
    const float* pb = em_b + ((size_t)b * TT + ts + row) * LL;
    for (int q = 0; q < nj; ++q) {
      int jj = jb + q;
      el[row][jj] = fexp2((pf[jj] + pb[jj]) * F_LOG2E);
    }
  }

  const bool lact = tid < 125;
  const int i  = tid / 5;          // output row 0..24
  const int jg = tid - 5 * i;      // col group 0..4
  const int j0 = 5 * jg;

  // ---- E' = exp(T)*2^-5, columns j0..j0+4, in registers (125 VGPR) ----
  float E[25][5];
  if (lact) {
#pragma unroll
    for (int k = 0; k < 25; ++k) {
      const float* tr = trans + k * 25 + j0;
#pragma unroll
      for (int u = 0; u < 5; ++u)
        E[k][u] = fexp2(tr[u] * F_LOG2E - 5.f);
    }
    // A = I
#pragma unroll
    for (int u = 0; u < 5; ++u)
      Al[0][i][j0 + u] = (i == j0 + u) ? 1.f : 0.f;
  }
  __syncthreads();

  int p = 0;
  const int s0 = (c == 0) ? 1 : 0;   // chunk 0 covers t = 1..63
  for (int st = s0; st < CLEN; ++st) {
    if (lact) {
      const float* ar = &Al[p][i][0];
      float4 q0 = *(const float4*)(ar);
      float4 q1 = *(const float4*)(ar + 4);
      float4 q2 = *(const float4*)(ar + 8);
      float4 q3 = *(const float4*)(ar + 12);
      float4 q4 = *(const float4*)(ar + 16);
      float4 q5 = *(const float4*)(ar + 20);
      float a24 = ar[24];
      float e0 = el[st][j0];
      float e1 = el[st][j0 + 1];
      float e2 = el[st][j0 + 2];
      float e3 = el[st][j0 + 3];
      float e4 = el[st][j0 + 4];
      float av[25] = {q0.x, q0.y, q0.z, q0.w, q1.x, q1.y, q1.z, q1.w,
                      q2.x, q2.y, q2.z, q2.w, q3.x, q3.y, q3.z, q3.w,
                      q4.x, q4.y, q4.z, q4.w, q5.x, q5.y, q5.z, q5.w, a24};
      float c0 = 0.f, c1 = 0.f, c2 = 0.f, c3 = 0.f, c4 = 0.f;
#pragma unroll
      for (int k = 0; k < 25; ++k) {
        float avk = av[k];
        c0 = fmaf(avk, E[k][0], c0);
        c1 = fmaf(avk, E[k][1], c1);
        c2 = fmaf(avk, E[k][2], c2);
        c3 = fmaf(avk, E[k][3], c3);
        c4 = fmaf(avk, E[k][4], c4);
      }
      float* wr = &Al[p ^ 1][i][j0];
      wr[0] = c0 * e0; wr[1] = c1 * e1; wr[2] = c2 * e2;
      wr[3] = c3 * e3; wr[4] = c4 * e4;
    }
    __syncthreads();
    p ^= 1;
  }

  // ---- store P transposed: g_PT[(b*8+c)*25 + j][i], row stride 28 ----
  if (lact) {
    const size_t base = ((size_t)(b * CHN + c)) * LL;
#pragma unroll
    for (int u = 0; u < 5; ++u)
      g_PT[(base + (j0 + u)) * 28 + i] = Al[p][i][j0 + u];
  }
}

__global__ __launch_bounds__(128) void crf_combine(
    const float* __restrict__ em_f, const float* __restrict__ em_b,
    const int* __restrict__ tags, const int* __restrict__ lengths,
    const float* __restrict__ trans,
    const float* __restrict__ startt, const float* __restrict__ endt,
    float* __restrict__ out)
{
  const int tid = threadIdx.x;
  const int b   = blockIdx.x;

  __shared__ __align__(16) float Vs[28];

  if (tid < 64) {
    // -------- wave 0: logZ via chunk-matrix chain --------
    const int lane = tid;
    const int j = (lane < LL) ? lane : 0;
    const float* ef0 = em_f + (size_t)b * TT * LL;
    const float* eb0 = em_b + (size_t)b * TT * LL;
    float v = fexp2((startt[j] + ef0[j] + eb0[j]) * F_LOG2E);  // alpha0
    float C = 0.f;  // accumulated log2 scale
    for (int c = 0; c < CHN; ++c) {
      if (lane < LL) Vs[lane] = v;
      wave_fence();
      float4 s0 = *(const float4*)(Vs);
      float4 s1 = *(const float4*)(Vs + 4);
      float4 s2 = *(const float4*)(Vs + 8);
      float4 s3 = *(const float4*)(Vs + 12);
      float4 s4 = *(const float4*)(Vs + 16);
      float4 s5 = *(const float4*)(Vs + 20);
      float s24 = Vs[24];
      wave_fence();
      const float* pr = g_PT + ((size_t)(b * CHN + c) * LL + j) * 28;
      float4 p0 = *(const float4*)(pr);
      float4 p1 = *(const float4*)(pr + 4);
      float4 p2 = *(const float4*)(pr + 8);
      float4 p3 = *(const float4*)(pr + 12);
      float4 p4 = *(const float4*)(pr + 16);
      float4 p5 = *(const float4*)(pr + 20);
      float p24 = pr[24];
      float nv = s0.x * p0.x;
      nv = fmaf(s0.y, p0.y, nv); nv = fmaf(s0.z, p0.z, nv); nv = fmaf(s0.w, p0.w, nv);
      nv = fmaf(s1.x, p1.x, nv); nv = fmaf(s1.y, p1.y, nv);
      nv = fmaf(s1.z, p1.z, nv); nv = fmaf(s1.w, p1.w, nv);
      nv = fmaf(s2.x, p2.x, nv); nv = fmaf(s2.y, p2.y, nv);
      nv = fmaf(s2.z, p2.z, nv); nv = fmaf(s2.w, p2.w, nv);
      nv = fmaf(s3.x, p3.x, nv); nv = fmaf(s3.y, p3.y, nv);
      nv = fmaf(s3.z, p3.z, nv); nv = fmaf(s3.w, p3.w, nv);
      nv = fmaf(s4.x, p4.x, nv); nv = fmaf(s4.y, p4.y, nv);
      nv = fmaf(s4.z, p4.z, nv); nv = fmaf(s4.w, p4.w, nv);
      nv = fmaf(s5.x, p5.x, nv); nv = fmaf(s5.y, p5.y, nv);
      nv = fmaf(s5.z, p5.z, nv); nv = fmaf(s5.w, p5.w, nv);
      nv = fmaf(s24, p24, nv);
      // renormalize by lane-0 exponent (all entries same magnitude class)
      float nv0 = rfl(nv);
      int k = ((__builtin_bit_cast(int, nv0) >> 23) & 255) - 127;
      k = (k > 100) ? 100 : ((k < -100) ? -100 : k);
      float scl = __builtin_bit_cast(float, (127 - k) << 23);
      v = nv * scl;
      C += (float)k;
    }
    float term = (lane < LL) ? v * fexp2(endt[j] * F_LOG2E) : 0.f;
    for (int o = 32; o > 0; o >>= 1) term += __shfl_down(term, o);
    if (lane == 0)
      atomicAdd(out, (flog2(term) + C + 5.f * 511.f) * F_LN2);
  } else {
    // -------- wave 1: gold path score --------
    const int lane = tid & 63;
    const int len = lengths[b];
    float acc = 0.f;
#pragma unroll
    for (int k = 0; k < 8; ++k) {
      int t = k * 64 + lane;
      int tg = tags[b * TT + t];
      size_t ei = ((size_t)b * TT + t) * LL + tg;
      float e = em_f[ei] + em_b[ei];
      float term;
      if (t == 0) term = startt[tg] + e;
      else        term = trans[tags[b * TT + t - 1] * LL + tg] + e;
      if (t == len - 1) term += endt[tg];
      if (t < len) acc += term;
    }
    for (int o = 32; o > 0; o >>= 1) acc += __shfl_down(acc, o);
    if (lane == 0) atomicAdd(out, -acc);
  }
}

extern "C" void kernel_launch(void* const* d_in, const int* in_sizes, int n_in,
                              void* d_out, int out_size, void* d_ws, size_t ws_size,
                              hipStream_t stream) {
  const int*   tok   = (const int*)d_in[0];
  const int*   tags  = (const int*)d_in[1];
  const int*   lens  = (const int*)d_in[2];
  const float* emb   = (const float*)d_in[3];
  const float* wif   = (const float*)d_in[4];
  const float* whf   = (const float*)d_in[5];
  const float* bif   = (const float*)d_in[6];
  const float* bhf   = (const float*)d_in[7];
  const float* wib   = (const float*)d_in[8];
  const float* whb   = (const float*)d_in[9];
  const float* bib   = (const float*)d_in[10];
  const float* bhb   = (const float*)d_in[11];
  const float* wtag  = (const float*)d_in[12];
  const float* btag  = (const float*)d_in[13];
  const float* trans = (const float*)d_in[14];
  const float* st    = (const float*)d_in[15];
  const float* en    = (const float*)d_in[16];

  char* wsb = (char*)d_ws;
  float* em_f = (float*)wsb;                                   //  6,553,600 B
  float* em_b = (float*)(wsb + 6553600);                       //  6,553,600 B

  hipMemsetAsync(d_out, 0, sizeof(float), stream);

  lstm_fused3<<<256, 512, 0, stream>>>(tok, emb, wif, wib, bif, bhf, bib, bhb,
                                       whf, whb, wtag, btag, em_f, em_b);
  crf_chunks<<<BB * CHN, 128, 0, stream>>>(em_f, em_b, trans);
  crf_combine<<<BB, 128, 0, stream>>>(em_f, em_b, tags, lens, trans, st, en,
                                      (float*)d_out);
}

// Round 3
// 410.701 us; speedup vs baseline: 1.0401x; 1.0395x over previous
//
#include <hip/hip_runtime.h>
#include <cstdint>
#include <cstddef>

#define BB 128
#define TT 512
#define DD 100
#define HH 100
#define NG 400   // 4*H
#define LL 25
#define TS 32    // scan tile (steps per burst)
#define NTILE 16
#define F_LOG2E 1.44269504088896340736f
#define F_LN2   0.69314718055994530942f

typedef __decltype(__builtin_amdgcn_cvt_pkrtz(0.f, 0.f)) h2_t;
typedef _Float16 v8h __attribute__((ext_vector_type(8)));
typedef float v4f __attribute__((ext_vector_type(4)));

__device__ __forceinline__ h2_t bc_h2(unsigned int u) {
  return __builtin_bit_cast(h2_t, u);
}
__device__ __forceinline__ unsigned int pk(float x, float y) {
  return __builtin_bit_cast(unsigned int, __builtin_amdgcn_cvt_pkrtz(x, y));
}
// round-to-nearest-even fp16 pack (matches old scalar (__fp16) h-store numerics)
__device__ __forceinline__ unsigned int pk_rte(float x, float y) {
  unsigned short a = __builtin_bit_cast(unsigned short, (__fp16)x);
  unsigned short c = __builtin_bit_cast(unsigned short, (__fp16)y);
  return (unsigned int)a | ((unsigned int)c << 16);
}

__device__ __forceinline__ float fdot2(h2_t a, h2_t b, float c) {
#if __has_builtin(__builtin_amdgcn_fdot2)
  return __builtin_amdgcn_fdot2(a, b, c, false);
#else
  return c + (float)a[0] * (float)b[0] + (float)a[1] * (float)b[1];
#endif
}

__device__ __forceinline__ float fexp2(float x) { return __builtin_amdgcn_exp2f(x); }
__device__ __forceinline__ float flog2(float x) { return __builtin_amdgcn_logf(x); }
__device__ __forceinline__ float frcp(float x)  { return __builtin_amdgcn_rcpf(x); }

__device__ __forceinline__ float sigmoid_f(float x) {
  return frcp(1.f + fexp2(-F_LOG2E * x));
}
__device__ __forceinline__ float tanh_f(float x) {
  float e = fexp2(2.f * F_LOG2E * x);
  return 1.f - 2.f * frcp(e + 1.f);
}

template <int CTRL>
__device__ __forceinline__ float qadd(float v) {
#if __has_builtin(__builtin_amdgcn_mov_dpp)
  int m = __builtin_amdgcn_mov_dpp(__builtin_bit_cast(int, v), CTRL, 0xF, 0xF, true);
  return v + __builtin_bit_cast(float, m);
#else
  int x = (CTRL == 177) ? 1 : 2;
  return v + __shfl_xor(v, x);
#endif
}

template <int LANE>
__device__ __forceinline__ float qbcast(float v) {
#if __has_builtin(__builtin_amdgcn_mov_dpp)
  int m = __builtin_amdgcn_mov_dpp(__builtin_bit_cast(int, v), LANE * 0x55, 0xF, 0xF, true);
  return __builtin_bit_cast(float, m);
#else
  return __shfl(v, (threadIdx.x & 63 & ~3) + LANE);
#endif
}

__device__ __forceinline__ float rfl(float v) {
  return __builtin_bit_cast(float,
      __builtin_amdgcn_readfirstlane(__builtin_bit_cast(int, v)));
}

__device__ __forceinline__ void wave_fence() {
#if __has_builtin(__builtin_amdgcn_wave_barrier)
  __builtin_amdgcn_wave_barrier();
#endif
}

// LDS-visibility-only barrier (vmcnt left free): imm 0xC07F.
__device__ __forceinline__ void lds_barrier() {
  __builtin_amdgcn_s_waitcnt(0xC07F);
  __builtin_amdgcn_s_barrier();
}

// ---------------------------------------------------------------------------
// FUSED BiLSTM + x-GEMM + emissions (v4).
// One block per (batch, dir), 512 thr / 8 waves.
//  - Waves 0-3: recurrent scan, 2-way k-split (lane = 2*j + s2, j=unit 0..99,
//    s2 = half of h dims). Each lane holds all 4 gate rows x 25 h2 weights
//    (100 VGPR), does 100 fdot2/step, ONE DPP pair-reduce, all 4 activations
//    in-lane. One scan wave per SIMD -> no co-wave issue contention, tight
//    per-step barrier. h packed 2/lane (DPP) -> b32 writes into split-padded
//    hls (words 0-24 | 28-52 so both halves are b128-aligned) + hhist tile.
//  - Waves 4-7: x-GEMM burst (3-4 B-cols each, unchanged) + EMISSION GEMM:
//    tile T-1's h (hhist) x w_tag via mfma_16x16x32_f16 during burst T,
//    stores em rows directly to global. Emissions no longer in the scan loop.
// ---------------------------------------------------------------------------
__global__ __launch_bounds__(512, 2) void lstm_fused4(
    const int* __restrict__ tok, const float* __restrict__ emb,
    const float* __restrict__ w_ih_f, const float* __restrict__ w_ih_b,
    const float* __restrict__ b_ih_f, const float* __restrict__ b_hh_f,
    const float* __restrict__ b_ih_b, const float* __restrict__ b_hh_b,
    const float* __restrict__ w_hh_f, const float* __restrict__ w_hh_b,
    const float* __restrict__ w_tag, const float* __restrict__ b_tag,
    float* __restrict__ em_f, float* __restrict__ em_b)
{
  const int tid = threadIdx.x;
  const int b   = blockIdx.x & 127;
  const int dir = blockIdx.x >> 7;
  const float* w_hh = dir ? w_hh_b : w_hh_f;
  const float* w_ih = dir ? w_ih_b : w_ih_f;
  const float* b_ih = dir ? b_ih_b : b_ih_f;
  const float* b_hh = dir ? b_hh_b : b_hh_f;
  float* emo = dir ? em_b : em_f;

  __shared__ __align__(16) unsigned short gin_lds[TS * 400];   // 25.6 KB
  __shared__ __align__(16) unsigned int xlds[TS * 68];         // 8.7 KB
  __shared__ __align__(16) unsigned int hhist[TS * 68];        // 8.7 KB (h history)
  __shared__ __align__(16) unsigned int hls0[56];
  __shared__ __align__(16) unsigned int hls1[56];

  // burst lane mapping
  const int wv   = tid >> 6;
  const int lane = tid & 63;
  const int l16  = lane & 15;
  const int quad = lane >> 4;
  const int c0b  = (25 * wv) >> 3;
  const int c1b  = (25 * (wv + 1)) >> 3;
  const int ncol = c1b - c0b;   // 3 or 4

  // ---- one-time: B fragments from global w_ih into registers ----
  v8h bfr[4][4];
  int pcol[4];
#pragma unroll
  for (int ci = 0; ci < 4; ++ci) {
    const int cc = (ci < ncol) ? (c0b + ci) : c0b;
    const int n  = 16 * cc + l16;
    const float* wr = w_ih + (size_t)n * DD;
#pragma unroll
    for (int f = 0; f < 3; ++f) {
      const float* wp = wr + f * 32 + quad * 8;
      float4 va = *(const float4*)(wp);
      float4 vb = *(const float4*)(wp + 4);
      uint4 u;
      u.x = pk(va.x, va.y); u.y = pk(va.z, va.w);
      u.z = pk(vb.x, vb.y); u.w = pk(vb.z, vb.w);
      bfr[ci][f] = __builtin_bit_cast(v8h, u);
    }
    {
      uint4 u = {0u, 0u, 0u, 0u};
      if (quad == 0) {
        float4 va = *(const float4*)(wr + 96);
        u.x = pk(va.x, va.y); u.y = pk(va.z, va.w);
      }
      bfr[ci][3] = __builtin_bit_cast(v8h, u);
    }
    const int qn = (n * 41) >> 12;            // n/100 for n<400
    pcol[ci] = ((n - 100 * qn) << 2) + qn;    // store permutation
  }

  // ---- xlds / hhist K-pad zero ----
  for (int i = tid; i < TS * 18; i += 512) {
    int row = i / 18;
    int d = i - row * 18;
    xlds[row * 68 + 50 + d] = 0u;
    hhist[row * 68 + 50 + d] = 0u;
  }

  // ---- scan state: waves 0-3, lane = 2*j + s2 ----
  const bool uact = tid < 200;
  const int j  = tid >> 1;
  const int s2 = tid & 1;

  h2_t wG0[25], wG1[25], wG2[25], wG3[25];
  float bias0 = 0.f, bias1 = 0.f, bias2 = 0.f, bias3 = 0.f;
  if (uact) {
    const float* r0 = w_hh + (size_t)(0 * 100 + j) * HH + 50 * s2;
    const float* r1 = w_hh + (size_t)(1 * 100 + j) * HH + 50 * s2;
    const float* r2 = w_hh + (size_t)(2 * 100 + j) * HH + 50 * s2;
    const float* r3 = w_hh + (size_t)(3 * 100 + j) * HH + 50 * s2;
#pragma unroll
    for (int d = 0; d < 25; ++d) {
      float2 v0 = *(const float2*)(r0 + 2 * d);
      float2 v1 = *(const float2*)(r1 + 2 * d);
      float2 v2 = *(const float2*)(r2 + 2 * d);
      float2 v3 = *(const float2*)(r3 + 2 * d);
      wG0[d] = __builtin_amdgcn_cvt_pkrtz(v0.x, v0.y);
      wG1[d] = __builtin_amdgcn_cvt_pkrtz(v1.x, v1.y);
      wG2[d] = __builtin_amdgcn_cvt_pkrtz(v2.x, v2.y);
      wG3[d] = __builtin_amdgcn_cvt_pkrtz(v3.x, v3.y);
    }
    bias0 = b_ih[j]       + b_hh[j];
    bias1 = b_ih[100 + j] + b_hh[100 + j];
    bias2 = b_ih[200 + j] + b_hh[200 + j];
    bias3 = b_ih[300 + j] + b_hh[300 + j];
  }

  // ---- emission GEMM state: waves 4-7 ----
  const int ew    = wv - 4;
  const int ecb   = ew & 1;          // label col-block (0: l 0-15, 1: l 16-24)
  const int erg   = (ew >> 1) & 1;   // step row-group (0: 0-15, 1: 16-31)
  const int encol = 16 * ecb + l16;  // output label index
  const bool eact2 = (wv >= 4) && (encol < LL);
  v8h etag[4];
  float ebias = 0.f;
  if (wv >= 4) {
#pragma unroll
    for (int f = 0; f < 3; ++f) {
      uint4 u = {0u, 0u, 0u, 0u};
      if (eact2) {
        const float* wp = w_tag + (size_t)encol * 200 + dir * 100 + f * 32 + quad * 8;
        float4 va = *(const float4*)(wp);
        float4 vb = *(const float4*)(wp + 4);
        u.x = pk(va.x, va.y); u.y = pk(va.z, va.w);
        u.z = pk(vb.x, vb.y); u.w = pk(vb.z, vb.w);
      }
      etag[f] = __builtin_bit_cast(v8h, u);
    }
    {
      uint4 u = {0u, 0u, 0u, 0u};
      if (eact2 && quad == 0) {
        float4 va = *(const float4*)(w_tag + (size_t)encol * 200 + dir * 100 + 96);
        u.x = pk(va.x, va.y); u.y = pk(va.z, va.w);
      }
      etag[3] = __builtin_bit_cast(v8h, u);
    }
    if (eact2 && dir == 0) ebias = b_tag[encol];
  }

  if (tid < 56) { hls0[tid] = 0u; hls1[tid] = 0u; }

  // x staging mapping: thread t<416 covers (row = t/13, seg = t%13)
  const int tprow = tid / 13;
  const int tps   = tid - 13 * tprow;
  const bool tp_act = tid < 416;

  // initial x prefetch (tile 0)
  float4 xa = {0, 0, 0, 0}, xb = {0, 0, 0, 0};
  if (tp_act) {
    int ii = tprow;
    int tt = dir ? (TT - 1 - ii) : ii;
    int tk = tok[b * TT + tt];
    const float* xp = emb + (size_t)tk * DD + 8 * tps;
    xa = *(const float4*)xp;
    if (tps < 12) xb = *(const float4*)(xp + 4);
  }

  float c = 0.f;
  uint2 gnext = {0u, 0u};

#define SD2(d, hw) { h2_t hv = bc_h2(hw);                                  \
  p0 = fdot2(wG0[d], hv, p0); p1 = fdot2(wG1[d], hv, p1);                  \
  p2 = fdot2(wG2[d], hv, p2); p3 = fdot2(wG3[d], hv, p3); }

#define SCAN2(HRD, HWR, ROW)                                               \
  {                                                                        \
    if (uact) {                                                            \
      uint2 gcurr = gnext;                                                 \
      int nr = ((ROW) < TS - 1) ? (ROW) + 1 : TS - 1;                      \
      gnext = ((const uint2*)(gin_lds + nr * 400))[j];                     \
      const unsigned int* hp = (HRD) + 28 * s2;                            \
      uint4 u0 = *((const uint4*)hp);                                      \
      uint4 u1 = *((const uint4*)(hp + 4));                                \
      uint4 u2 = *((const uint4*)(hp + 8));                                \
      uint4 u3 = *((const uint4*)(hp + 12));                               \
      uint4 u4 = *((const uint4*)(hp + 16));                               \
      uint4 u5 = *((const uint4*)(hp + 20));                               \
      unsigned int u6 = hp[24];                                            \
      float p0 = 0.f, p1 = 0.f, p2 = 0.f, p3 = 0.f;                        \
      SD2(0, u0.x)  SD2(1, u0.y)  SD2(2, u0.z)  SD2(3, u0.w)               \
      SD2(4, u1.x)  SD2(5, u1.y)  SD2(6, u1.z)  SD2(7, u1.w)               \
      SD2(8, u2.x)  SD2(9, u2.y)  SD2(10, u2.z) SD2(11, u2.w)              \
      SD2(12, u3.x) SD2(13, u3.y) SD2(14, u3.z) SD2(15, u3.w)              \
      SD2(16, u4.x) SD2(17, u4.y) SD2(18, u4.z) SD2(19, u4.w)              \
      SD2(20, u5.x) SD2(21, u5.y) SD2(22, u5.z) SD2(23, u5.w)              \
      SD2(24, u6)                                                          \
      p0 = qadd<177>(p0); p1 = qadd<177>(p1);                              \
      p2 = qadd<177>(p2); p3 = qadd<177>(p3);                              \
      h2_t glo = bc_h2(gcurr.x), ghi = bc_h2(gcurr.y);                     \
      float gi = p0 + bias0 + (float)glo[0];                               \
      float gf = p1 + bias1 + (float)glo[1];                               \
      float gg = p2 + bias2 + (float)ghi[0];                               \
      float go = p3 + bias3 + (float)ghi[1];                               \
      float iv = sigmoid_f(gi);                                            \
      float fv = sigmoid_f(gf);                                            \
      float gv = tanh_f(gg);                                               \
      float ov = sigmoid_f(go);                                            \
      c = fmaf(fv, c, iv * gv);                                            \
      float hvv = ov * tanh_f(c);                                          \
      float hnb = qbcast<2>(hvv);                                          \
      if ((tid & 3) == 0) {                                                \
        int k = tid >> 2;                                                  \
        unsigned int val = pk_rte(hvv, hnb);                               \
        (HWR)[k + (k >= 25 ? 3 : 0)] = val;                                \
        hhist[(ROW) * 68 + k] = val;                                       \
      }                                                                    \
    }                                                                      \
    lds_barrier();                                                         \
  }

#define EMIT_GEMM(TB)                                                      \
  {                                                                        \
    const unsigned int* hb = hhist + (erg * 16 + l16) * 68 + quad * 4;     \
    v8h ah0 = __builtin_bit_cast(v8h, *(const uint4*)(hb));                \
    v8h ah1 = __builtin_bit_cast(v8h, *(const uint4*)(hb + 16));           \
    v8h ah2 = __builtin_bit_cast(v8h, *(const uint4*)(hb + 32));           \
    v8h ah3 = __builtin_bit_cast(v8h, *(const uint4*)(hb + 48));           \
    v4f ea = {0.f, 0.f, 0.f, 0.f};                                         \
    ea = __builtin_amdgcn_mfma_f32_16x16x32_f16(ah0, etag[0], ea, 0, 0, 0);\
    ea = __builtin_amdgcn_mfma_f32_16x16x32_f16(ah1, etag[1], ea, 0, 0, 0);\
    ea = __builtin_amdgcn_mfma_f32_16x16x32_f16(ah2, etag[2], ea, 0, 0, 0);\
    ea = __builtin_amdgcn_mfma_f32_16x16x32_f16(ah3, etag[3], ea, 0, 0, 0);\
    if (eact2) {                                                           \
      const int tb = (TB) + erg * 16 + quad * 4;                           \
      _Pragma("unroll")                                                    \
      for (int r = 0; r < 4; ++r) {                                        \
        int t = dir ? (TT - 1 - (tb + r)) : (tb + r);                      \
        emo[((size_t)b * TT + t) * LL + encol] = ea[r] + ebias;            \
      }                                                                    \
    }                                                                      \
  }

  __syncthreads();  // pads / hls init complete

  for (int T = 0; T < NTILE; ++T) {
    // ---- write prefetched x regs to xlds ----
    if (tp_act) {
      unsigned int* xr = xlds + tprow * 68 + 4 * tps;
      if (tps < 12) {
        uint4 u;
        u.x = pk(xa.x, xa.y); u.y = pk(xa.z, xa.w);
        u.z = pk(xb.x, xb.y); u.w = pk(xb.z, xb.w);
        *(uint4*)xr = u;
      } else {
        xr[0] = pk(xa.x, xa.y);
        xr[1] = pk(xa.z, xa.w);
      }
    }
    __syncthreads();

    // ---- BURST ----
    {
      v8h af[2][4];
#pragma unroll
      for (int rg = 0; rg < 2; ++rg)
#pragma unroll
        for (int f = 0; f < 4; ++f)
          af[rg][f] = __builtin_bit_cast(v8h,
              *(const uint4*)(xlds + (rg * 16 + l16) * 68 + f * 16 + quad * 4));

      // kick off next tile's x prefetch (stays in flight through the scan)
      if (tp_act && T + 1 < NTILE) {
        int ii = (T + 1) * TS + tprow;
        int tt = dir ? (TT - 1 - ii) : ii;
        int tk = tok[b * TT + tt];
        const float* xp = emb + (size_t)tk * DD + 8 * tps;
        xa = *(const float4*)xp;
        if (tps < 12) xb = *(const float4*)(xp + 4);
      }

      __fp16* gout = (__fp16*)gin_lds;
#pragma unroll
      for (int ci = 0; ci < 4; ++ci) {
        if (ci >= ncol) break;
        const int p = pcol[ci];
#pragma unroll
        for (int rg = 0; rg < 2; ++rg) {
          v4f acc = {0.f, 0.f, 0.f, 0.f};
          acc = __builtin_amdgcn_mfma_f32_16x16x32_f16(af[rg][0], bfr[ci][0], acc, 0, 0, 0);
          acc = __builtin_amdgcn_mfma_f32_16x16x32_f16(af[rg][1], bfr[ci][1], acc, 0, 0, 0);
          acc = __builtin_amdgcn_mfma_f32_16x16x32_f16(af[rg][2], bfr[ci][2], acc, 0, 0, 0);
          acc = __builtin_amdgcn_mfma_f32_16x16x32_f16(af[rg][3], bfr[ci][3], acc, 0, 0, 0);
          const int rowb = rg * 16 + quad * 4;
#pragma unroll
          for (int r = 0; r < 4; ++r)
            gout[(rowb + r) * 400 + p] = (__fp16)acc[r];
        }
      }

      // ---- emission GEMM for previous tile's h (waves 4-7) ----
      if (wv >= 4 && T > 0) {
        EMIT_GEMM((T - 1) * TS)
      }
    }
    __syncthreads();
    if (uact) gnext = ((const uint2*)gin_lds)[j];

    // ---- TS scan steps ----
    for (int it = 0; it < TS; it += 2) {
      SCAN2(hls0, hls1, it)
      SCAN2(hls1, hls0, it + 1)
    }
  }

  // epilogue: emissions for the final tile (hhist holds tile NTILE-1's h;
  // last scan step ended with lds_barrier, so it is visible)
  if (wv >= 4) {
    EMIT_GEMM((NTILE - 1) * TS)
  }
#undef EMIT_GEMM
#undef SCAN2
#undef SD2
}

// ===========================================================================
// CRF v3 — parallel chunked scan (unchanged from round 1; verified).
// ===========================================================================
#define CHN  8
#define CLEN 64
__device__ __align__(16) float g_PT[(size_t)BB * CHN * LL * 28];  // 2.87 MB

__global__ __launch_bounds__(128, 2) void crf_chunks(
    const float* __restrict__ em_f, const float* __restrict__ em_b,
    const float* __restrict__ trans)
{
  const int tid = threadIdx.x;
  const int b   = blockIdx.x >> 3;
  const int c   = blockIdx.x & 7;
  const int ts  = c * CLEN;

  __shared__ __align__(16) float Al[2][LL][28];   // double-buffered A
  __shared__ __align__(16) float el[CLEN][32];    // e_t[j] = exp(em_t[j])

  // ---- stage e rows (2 threads per time step) ----
  {
    const int row  = tid >> 1;        // 0..63
    const int half = tid & 1;
    const int jb   = half ? 13 : 0;
    const int nj   = half ? 12 : 13;
    const float* pf = em_f + ((size_t)b * TT + ts + row) * LL;
    const float* pb = em_b + ((size_t)b * TT + ts + row) * LL;
    for (int q = 0; q < nj; ++q) {
      int jj = jb + q;
      el[row][jj] = fexp2((pf[jj] + pb[jj]) * F_LOG2E);
    }
  }

  const bool lact = tid < 125;
  const int i  = tid / 5;          // output row 0..24
  const int jg = tid - 5 * i;      // col group 0..4
  const int j0 = 5 * jg;

  // ---- E' = exp(T)*2^-5, columns j0..j0+4, in registers (125 VGPR) ----
  float E[25][5];
  if (lact) {
#pragma unroll
    for (int k = 0; k < 25; ++k) {
      const float* tr = trans + k * 25 + j0;
#pragma unroll
      for (int u = 0; u < 5; ++u)
        E[k][u] = fexp2(tr[u] * F_LOG2E - 5.f);
    }
    // A = I
#pragma unroll
    for (int u = 0; u < 5; ++u)
      Al[0][i][j0 + u] = (i == j0 + u) ? 1.f : 0.f;
  }
  __syncthreads();

  int p = 0;
  const int s0 = (c == 0) ? 1 : 0;   // chunk 0 covers t = 1..63
  for (int st = s0; st < CLEN; ++st) {
    if (lact) {
      const float* ar = &Al[p][i][0];
      float4 q0 = *(const float4*)(ar);
      float4 q1 = *(const float4*)(ar + 4);
      float4 q2 = *(const float4*)(ar + 8);
      float4 q3 = *(const float4*)(ar + 12);
      float4 q4 = *(const float4*)(ar + 16);
      float4 q5 = *(const float4*)(ar + 20);
      float a24 = ar[24];
      float e0 = el[st][j0];
      float e1 = el[st][j0 + 1];
      float e2 = el[st][j0 + 2];
      float e3 = el[st][j0 + 3];
      float e4 = el[st][j0 + 4];
      float av[25] = {q0.x, q0.y, q0.z, q0.w, q1.x, q1.y, q1.z, q1.w,
                      q2.x, q2.y, q2.z, q2.w, q3.x, q3.y, q3.z, q3.w,
                      q4.x, q4.y, q4.z, q4.w, q5.x, q5.y, q5.z, q5.w, a24};
      float c0 = 0.f, c1 = 0.f, c2 = 0.f, c3 = 0.f, c4 = 0.f;
#pragma unroll
      for (int k = 0; k < 25; ++k) {
        float avk = av[k];
        c0 = fmaf(avk, E[k][0], c0);
        c1 = fmaf(avk, E[k][1], c1);
        c2 = fmaf(avk, E[k][2], c2);
        c3 = fmaf(avk, E[k][3], c3);
        c4 = fmaf(avk, E[k][4], c4);
      }
      float* wr = &Al[p ^ 1][i][j0];
      wr[0] = c0 * e0; wr[1] = c1 * e1; wr[2] = c2 * e2;
      wr[3] = c3 * e3; wr[4] = c4 * e4;
    }
    __syncthreads();
    p ^= 1;
  }

  // ---- store P transposed: g_PT[(b*8+c)*25 + j][i], row stride 28 ----
  if (lact) {
    const size_t base = ((size_t)(b * CHN + c)) * LL;
#pragma unroll
    for (int u = 0; u < 5; ++u)
      g_PT[(base + (j0 + u)) * 28 + i] = Al[p][i][j0 + u];
  }
}

__global__ __launch_bounds__(128) void crf_combine(
    const float* __restrict__ em_f, const float* __restrict__ em_b,
    const int* __restrict__ tags, const int* __restrict__ lengths,
    const float* __restrict__ trans,
    const float* __restrict__ startt, const float* __restrict__ endt,
    float* __restrict__ out)
{
  const int tid = threadIdx.x;
  const int b   = blockIdx.x;

  __shared__ __align__(16) float Vs[28];

  if (tid < 64) {
    // -------- wave 0: logZ via chunk-matrix chain --------
    const int lane = tid;
    const int j = (lane < LL) ? lane : 0;
    const float* ef0 = em_f + (size_t)b * TT * LL;
    const float* eb0 = em_b + (size_t)b * TT * LL;
    float v = fexp2((startt[j] + ef0[j] + eb0[j]) * F_LOG2E);  // alpha0
    float C = 0.f;  // accumulated log2 scale
    for (int c = 0; c < CHN; ++c) {
      if (lane < LL) Vs[lane] = v;
      wave_fence();
      float4 s0 = *(const float4*)(Vs);
      float4 s1 = *(const float4*)(Vs + 4);
      float4 s2 = *(const float4*)(Vs + 8);
      float4 s3 = *(const float4*)(Vs + 12);
      float4 s4 = *(const float4*)(Vs + 16);
      float4 s5 = *(const float4*)(Vs + 20);
      float s24 = Vs[24];
      wave_fence();
      const float* pr = g_PT + ((size_t)(b * CHN + c) * LL + j) * 28;
      float4 p0 = *(const float4*)(pr);
      float4 p1 = *(const float4*)(pr + 4);
      float4 p2 = *(const float4*)(pr + 8);
      float4 p3 = *(const float4*)(pr + 12);
      float4 p4 = *(const float4*)(pr + 16);
      float4 p5 = *(const float4*)(pr + 20);
      float p24 = pr[24];
      float nv = s0.x * p0.x;
      nv = fmaf(s0.y, p0.y, nv); nv = fmaf(s0.z, p0.z, nv); nv = fmaf(s0.w, p0.w, nv);
      nv = fmaf(s1.x, p1.x, nv); nv = fmaf(s1.y, p1.y, nv);
      nv = fmaf(s1.z, p1.z, nv); nv = fmaf(s1.w, p1.w, nv);
      nv = fmaf(s2.x, p2.x, nv); nv = fmaf(s2.y, p2.y, nv);
      nv = fmaf(s2.z, p2.z, nv); nv = fmaf(s2.w, p2.w, nv);
      nv = fmaf(s3.x, p3.x, nv); nv = fmaf(s3.y, p3.y, nv);
      nv = fmaf(s3.z, p3.z, nv); nv = fmaf(s3.w, p3.w, nv);
      nv = fmaf(s4.x, p4.x, nv); nv = fmaf(s4.y, p4.y, nv);
      nv = fmaf(s4.z, p4.z, nv); nv = fmaf(s4.w, p4.w, nv);
      nv = fmaf(s5.x, p5.x, nv); nv = fmaf(s5.y, p5.y, nv);
      nv = fmaf(s5.z, p5.z, nv); nv = fmaf(s5.w, p5.w, nv);
      nv = fmaf(s24, p24, nv);
      // renormalize by lane-0 exponent (all entries same magnitude class)
      float nv0 = rfl(nv);
      int k = ((__builtin_bit_cast(int, nv0) >> 23) & 255) - 127;
      k = (k > 100) ? 100 : ((k < -100) ? -100 : k);
      float scl = __builtin_bit_cast(float, (127 - k) << 23);
      v = nv * scl;
      C += (float)k;
    }
    float term = (lane < LL) ? v * fexp2(endt[j] * F_LOG2E) : 0.f;
    for (int o = 32; o > 0; o >>= 1) term += __shfl_down(term, o);
    if (lane == 0)
      atomicAdd(out, (flog2(term) + C + 5.f * 511.f) * F_LN2);
  } else {
    // -------- wave 1: gold path score --------
    const int lane = tid & 63;
    const int len = lengths[b];
    float acc = 0.f;
#pragma unroll
    for (int k = 0; k < 8; ++k) {
      int t = k * 64 + lane;
      int tg = tags[b * TT + t];
      size_t ei = ((size_t)b * TT + t) * LL + tg;
      float e = em_f[ei] + em_b[ei];
      float term;
      if (t == 0) term = startt[tg] + e;
      else        term = trans[tags[b * TT + t - 1] * LL + tg] + e;
      if (t == len - 1) term += endt[tg];
      if (t < len) acc += term;
    }
    for (int o = 32; o > 0; o >>= 1) acc += __shfl_down(acc, o);
    if (lane == 0) atomicAdd(out, -acc);
  }
}

extern "C" void kernel_launch(void* const* d_in, const int* in_sizes, int n_in,
                              void* d_out, int out_size, void* d_ws, size_t ws_size,
                              hipStream_t stream) {
  const int*   tok   = (const int*)d_in[0];
  const int*   tags  = (const int*)d_in[1];
  const int*   lens  = (const int*)d_in[2];
  const float* emb   = (const float*)d_in[3];
  const float* wif   = (const float*)d_in[4];
  const float* whf   = (const float*)d_in[5];
  const float* bif   = (const float*)d_in[6];
  const float* bhf   = (const float*)d_in[7];
  const float* wib   = (const float*)d_in[8];
  const float* whb   = (const float*)d_in[9];
  const float* bib   = (const float*)d_in[10];
  const float* bhb   = (const float*)d_in[11];
  const float* wtag  = (const float*)d_in[12];
  const float* btag  = (const float*)d_in[13];
  const float* trans = (const float*)d_in[14];
  const float* st    = (const float*)d_in[15];
  const float* en    = (const float*)d_in[16];

  char* wsb = (char*)d_ws;
  float* em_f = (float*)wsb;                                   //  6,553,600 B
  float* em_b = (float*)(wsb + 6553600);                       //  6,553,600 B

  hipMemsetAsync(d_out, 0, sizeof(float), stream);

  lstm_fused4<<<256, 512, 0, stream>>>(tok, emb, wif, wib, bif, bhf, bib, bhb,
                                       whf, whb, wtag, btag, em_f, em_b);
  crf_chunks<<<BB * CHN, 128, 0, stream>>>(em_f, em_b, trans);
  crf_combine<<<BB, 128, 0, stream>>>(em_f, em_b, tags, lens, trans, st, en,
                                      (float*)d_out);
}